// Round 1
// baseline (463.305 us; speedup 1.0000x reference)
//
#include <hip/hip_runtime.h>

// MMD loss, N=8192 total rows (4096 X + 4096 Y), D=64, f32.
// Pass 1: sum of clamped pairwise squared L2 -> bandwidth.
// Pass 2: S = sum_ij s_i s_j K_ij, K = u^4+u^2+u+sqrt(u)+sqrt(sqrt(u)), u=exp(-L2/bw).
// out = S / 4096^2.

#define NX_   4096
#define NT_   8192
#define DD    64
#define BLK_I 512   // i-rows per block (== threads)
#define BLK_J 512   // j-range per block
#define TJ    128   // j-rows staged in LDS per tile
#define NTH   512

__global__ void sq_kernel(const float* __restrict__ X, const float* __restrict__ Y,
                          float* __restrict__ sq)
{
    int i = blockIdx.x * blockDim.x + threadIdx.x;
    if (i >= NT_) return;
    const float4* z = (const float4*)((i < NX_) ? (X + (size_t)i * DD)
                                                : (Y + (size_t)(i - NX_) * DD));
    float s0 = 0.f, s1 = 0.f, s2 = 0.f, s3 = 0.f;
#pragma unroll
    for (int q = 0; q < 16; ++q) {
        float4 v = z[q];
        s0 = fmaf(v.x, v.x, s0);
        s1 = fmaf(v.y, v.y, s1);
        s2 = fmaf(v.z, v.z, s2);
        s3 = fmaf(v.w, v.w, s3);
    }
    sq[i] = (s0 + s1) + (s2 + s3);
}

__device__ __forceinline__ float kern5(float t) {
    // sum over bandwidth mults [0.25,0.5,1,2,4] of exp(-t/m) with t = L2/bw
    float u  = __expf(-t);
    float u2 = u * u;
    float u4 = u2 * u2;
    float su = sqrtf(u);
    float qu = sqrtf(su);
    return ((u4 + u2) + (u + su)) + qu;
}

template <int PASS>
__global__ __launch_bounds__(NTH)
void mmd_pass(const float* __restrict__ X, const float* __restrict__ Y,
              const float* __restrict__ sq, double* __restrict__ accum)
{
    __shared__ float ldsj[TJ * DD];   // 32 KiB j-tile
    __shared__ float ldsq[TJ];        // sq of tile rows

    const int tid = threadIdx.x;
    const int ib = blockIdx.x, jb = blockIdx.y;
    const int i = ib * BLK_I + tid;

    const float4* zp = (const float4*)((i < NX_) ? (X + (size_t)i * DD)
                                                 : (Y + (size_t)(i - NX_) * DD));
    float4 zi[16];
#pragma unroll
    for (int q = 0; q < 16; ++q) zi[q] = zp[q];
    const float sqi = sq[i];

    float inv_bw = 0.f;
    if (PASS == 2) {
        double sl2 = accum[0];  // finalized by pass 1 (stream ordering)
        inv_bw = (float)((((double)NT_ * (double)NT_) - (double)NT_) / sl2);
    }

    double local = 0.0;
    const int j0 = jb * BLK_J;

    for (int jt = 0; jt < BLK_J; jt += TJ) {
        __syncthreads();  // protect previous tile from overwrite
        const int base = j0 + jt;
#pragma unroll
        for (int q = 0; q < 4; ++q) {
            int idx = tid + q * NTH;        // float4 slot in tile [0, TJ*DD/4)
            int row = idx >> 4;             // 16 float4 per row
            int c4  = idx & 15;
            int gr  = base + row;
            const float4* src = (const float4*)((gr < NX_) ? (X + (size_t)gr * DD)
                                                           : (Y + (size_t)(gr - NX_) * DD));
            ((float4*)ldsj)[idx] = src[c4];
        }
        if (tid < TJ) ldsq[tid] = sq[base + tid];
        __syncthreads();

        float chunk = 0.f;
        for (int j = 0; j < TJ; j += 4) {
            const float4* r0 = (const float4*)&ldsj[(j + 0) * DD];
            const float4* r1 = (const float4*)&ldsj[(j + 1) * DD];
            const float4* r2 = (const float4*)&ldsj[(j + 2) * DD];
            const float4* r3 = (const float4*)&ldsj[(j + 3) * DD];
            float a0 = 0.f, a1 = 0.f, a2 = 0.f, a3 = 0.f;
#pragma unroll
            for (int q = 0; q < 16; ++q) {
                float4 z  = zi[q];
                float4 b0 = r0[q], b1 = r1[q], b2 = r2[q], b3 = r3[q];
                a0 = fmaf(z.x, b0.x, a0); a0 = fmaf(z.y, b0.y, a0);
                a0 = fmaf(z.z, b0.z, a0); a0 = fmaf(z.w, b0.w, a0);
                a1 = fmaf(z.x, b1.x, a1); a1 = fmaf(z.y, b1.y, a1);
                a1 = fmaf(z.z, b1.z, a1); a1 = fmaf(z.w, b1.w, a1);
                a2 = fmaf(z.x, b2.x, a2); a2 = fmaf(z.y, b2.y, a2);
                a2 = fmaf(z.z, b2.z, a2); a2 = fmaf(z.w, b2.w, a2);
                a3 = fmaf(z.x, b3.x, a3); a3 = fmaf(z.y, b3.y, a3);
                a3 = fmaf(z.z, b3.z, a3); a3 = fmaf(z.w, b3.w, a3);
            }
            float l0 = fmaxf(fmaf(-2.f, a0, sqi + ldsq[j + 0]), 0.f);
            float l1 = fmaxf(fmaf(-2.f, a1, sqi + ldsq[j + 1]), 0.f);
            float l2 = fmaxf(fmaf(-2.f, a2, sqi + ldsq[j + 2]), 0.f);
            float l3 = fmaxf(fmaf(-2.f, a3, sqi + ldsq[j + 3]), 0.f);
            if (PASS == 1) {
                chunk += ((l0 + l1) + (l2 + l3));
            } else {
                chunk += ((kern5(l0 * inv_bw) + kern5(l1 * inv_bw)) +
                          (kern5(l2 * inv_bw) + kern5(l3 * inv_bw)));
            }
        }
        local += (double)chunk;
    }

    // wave-level f64 reduce, then one atomic per wave
#pragma unroll
    for (int off = 32; off; off >>= 1) local += __shfl_down(local, off);
    if ((tid & 63) == 0) {
        if (PASS == 1) {
            atomicAdd(accum, local);
        } else {
            // sign = s_i * s_j, uniform per (i-block, j-block)
            bool pos = ((ib < (NX_ / BLK_I)) == (jb < (NX_ / BLK_J)));
            atomicAdd(accum + 1, pos ? local : -local);
        }
    }
}

__global__ void fin_kernel(const double* __restrict__ accum, float* __restrict__ out)
{
    out[0] = (float)(accum[1] * (1.0 / ((double)NX_ * (double)NX_)));
}

extern "C" void kernel_launch(void* const* d_in, const int* in_sizes, int n_in,
                              void* d_out, int out_size, void* d_ws, size_t ws_size,
                              hipStream_t stream)
{
    const float* X = (const float*)d_in[0];
    const float* Y = (const float*)d_in[1];
    double* accum = (double*)d_ws;                 // [0]=sumL2, [1]=S
    float*  sq    = (float*)((char*)d_ws + 64);    // 8192 f32

    hipMemsetAsync(d_ws, 0, 64, stream);           // zero accumulators (ws is poisoned)
    sq_kernel<<<NT_ / 256, 256, 0, stream>>>(X, Y, sq);

    dim3 grid(NT_ / BLK_I, NT_ / BLK_J);           // 16 x 16 = 256 blocks
    mmd_pass<1><<<grid, NTH, 0, stream>>>(X, Y, sq, accum);
    mmd_pass<2><<<grid, NTH, 0, stream>>>(X, Y, sq, accum);
    fin_kernel<<<1, 1, 0, stream>>>(accum, (float*)d_out);
}

// Round 2
// 164.149 us; speedup vs baseline: 2.8225x; 2.8225x over previous
//
#include <hip/hip_runtime.h>

// MMD loss via MFMA. N=8192 rows (4096 X + 4096 Y), D=64, f32 in, f32 scalar out.
//   bandwidth: closed form  sum_ij L2 = 2N*sum(sq) - 2*||sum z||^2   (O(N*d))
//   main pass: dot(z_i,z_j) via bf16 split (hh+hl+lh) MFMA 16x16x32,
//              x = s*L2 = c2*dot + s*(sq_i+sq_j),  s = -log2(e)/bw
//              K5 = u^4+u^2+u+sqrt(u)+sqrt(sqrt(u)), u = 2^min(x,0)
//   out = (sum_ij sign_ij * K5_ij) / 4096^2

#define NX 4096
#define NT 8192
#define DD 64

using f32x4 = __attribute__((ext_vector_type(4))) float;
using s8v   = __attribute__((ext_vector_type(8))) short;   // 8 bf16 = 4 VGPR

__device__ __forceinline__ float fast_exp2(float x) {
#if __has_builtin(__builtin_amdgcn_exp2f)
    return __builtin_amdgcn_exp2f(x);
#else
    return exp2f(x);
#endif
}
__device__ __forceinline__ float fast_sqrt(float x) {
#if __has_builtin(__builtin_amdgcn_sqrtf)
    return __builtin_amdgcn_sqrtf(x);
#else
    return sqrtf(x);
#endif
}

__device__ __forceinline__ ushort f2bf(float f) {          // RTNE f32 -> bf16 bits
    unsigned u = __float_as_uint(f);
    unsigned r = u + 0x7fffu + ((u >> 16) & 1u);
    return (ushort)(r >> 16);
}
__device__ __forceinline__ float bf2f(ushort h) {
    return __uint_as_float((unsigned)h << 16);
}

__device__ __forceinline__ const float* zrow(const float* X, const float* Y, int i) {
    return (i < NX) ? (X + (size_t)i * DD) : (Y + (size_t)(i - NX) * DD);
}

// ---- per-row squared norms + global sum(sq) -------------------------------
__global__ void k_sq(const float* __restrict__ X, const float* __restrict__ Y,
                     float* __restrict__ sq, double* __restrict__ sumsq)
{
    __shared__ float lds[16];
    const int tid = threadIdx.x;
    const int row = blockIdx.x * 16 + (tid >> 4);
    const int sub = tid & 15;
    const float4* p = (const float4*)zrow(X, Y, row);
    float4 v = p[sub];
    float d = v.x * v.x + v.y * v.y + v.z * v.z + v.w * v.w;
#pragma unroll
    for (int m = 1; m < 16; m <<= 1) d += __shfl_xor(d, m);
    if (sub == 0) { sq[row] = d; lds[tid >> 4] = d; }
    __syncthreads();
    if (tid == 0) {
        float s = 0.f;
#pragma unroll
        for (int g = 0; g < 16; ++g) s += lds[g];
        atomicAdd(sumsq, (double)s);
    }
}

// ---- column sums of Z (for ||sum z||^2) -----------------------------------
__global__ void k_col(const float* __restrict__ X, const float* __restrict__ Y,
                      float* __restrict__ colsum)
{
    __shared__ float4 lds[256];
    const int tid = threadIdx.x, bid = blockIdx.x;
    const float4* p = (bid < 16) ? ((const float4*)X + (size_t)bid * 4096)
                                 : ((const float4*)Y + (size_t)(bid - 16) * 4096);
    float4 a = make_float4(0.f, 0.f, 0.f, 0.f);
    for (int k = 0; k < 16; ++k) {                 // 256 rows per block, coalesced
        float4 v = p[tid + k * 256];               // col-group = tid & 15, invariant
        a.x += v.x; a.y += v.y; a.z += v.z; a.w += v.w;
    }
    lds[tid] = a;
    __syncthreads();
    if (tid < 16) {
        float4 s = lds[tid];
        for (int g = 1; g < 16; ++g) {
            float4 t = lds[tid + g * 16];
            s.x += t.x; s.y += t.y; s.z += t.z; s.w += t.w;
        }
        atomicAdd(colsum + tid * 4 + 0, s.x);
        atomicAdd(colsum + tid * 4 + 1, s.y);
        atomicAdd(colsum + tid * 4 + 2, s.z);
        atomicAdd(colsum + tid * 4 + 3, s.w);
    }
}

// ---- bandwidth -> exponent scale constants --------------------------------
__global__ void k_bw(const double* __restrict__ sumsq, const float* __restrict__ colsum,
                     float* __restrict__ cs)
{
    double s2 = 0.0;
    for (int c = 0; c < 64; ++c) { double v = (double)colsum[c]; s2 += v * v; }
    double sumL2 = 2.0 * (double)NT * sumsq[0] - 2.0 * s2;
    double bw = sumL2 / ((double)NT * (double)NT - (double)NT);
    double s = -1.4426950408889634 / bw;       // -log2(e)/bw
    cs[0] = (float)s;
    cs[1] = (float)(-2.0 * s);
}

// ---- bf16 hi/lo split of Z ------------------------------------------------
__global__ void k_split(const float* __restrict__ X, const float* __restrict__ Y,
                        ushort* __restrict__ ZH, ushort* __restrict__ ZL)
{
    const int t = blockIdx.x * blockDim.x + threadIdx.x;   // float4 index, 131072 total
    const float4* src = (t < 65536) ? ((const float4*)X + t)
                                    : ((const float4*)Y + (t - 65536));
    float4 v = *src;
    float c[4] = {v.x, v.y, v.z, v.w};
    ushort h[4], l[4];
#pragma unroll
    for (int q = 0; q < 4; ++q) {
        h[q] = f2bf(c[q]);
        l[q] = f2bf(c[q] - bf2f(h[q]));
    }
    *(ushort4*)(ZH + (size_t)t * 4) = make_ushort4(h[0], h[1], h[2], h[3]);
    *(ushort4*)(ZL + (size_t)t * 4) = make_ushort4(l[0], l[1], l[2], l[3]);
}

// ---- main pairwise pass ---------------------------------------------------
// grid (32, 64): block tile 256(i) x 128(j); 8 waves arranged 4x2, wave tile 64x64.
__device__ __forceinline__ void combo(const ushort* __restrict__ PA,
                                      const ushort* __restrict__ PB, int ks,
                                      int arow, int brow, int koff, f32x4 acc[4][4])
{
    s8v b[4];
#pragma unroll
    for (int cg = 0; cg < 4; ++cg)
        b[cg] = *(const s8v*)(PB + (size_t)(brow + cg * 16) * DD + ks * 32 + koff);
#pragma unroll
    for (int rg = 0; rg < 4; ++rg) {
        s8v a = *(const s8v*)(PA + (size_t)(arow + rg * 16) * DD + ks * 32 + koff);
#pragma unroll
        for (int cg = 0; cg < 4; ++cg)
            acc[rg][cg] = __builtin_amdgcn_mfma_f32_16x16x32_bf16(a, b[cg], acc[rg][cg], 0, 0, 0);
    }
}

__global__ __launch_bounds__(512)
void k_main(const ushort* __restrict__ ZH, const ushort* __restrict__ ZL,
            const float* __restrict__ sq, const float* __restrict__ cs,
            double* __restrict__ accS)
{
    __shared__ double sred[8];
    const int tid = threadIdx.x;
    const int lane = tid & 63, wid = tid >> 6;
    const int wr = wid >> 1, wc = wid & 1;            // 4 x 2 wave grid
    const int ib = blockIdx.x, jb = blockIdx.y;
    const int rbase = ib * 256 + wr * 64;
    const int cbase = jb * 128 + wc * 64;
    const int l15 = lane & 15, lh = lane >> 4;
    const int koff = lh * 8;
    const int arow = rbase + l15;
    const int brow = cbase + l15;

    f32x4 acc[4][4];
#pragma unroll
    for (int rg = 0; rg < 4; ++rg)
#pragma unroll
        for (int cg = 0; cg < 4; ++cg)
            acc[rg][cg] = (f32x4){0.f, 0.f, 0.f, 0.f};

    // hh (k=0,1), hl, lh  -- ll dropped (~2^-18 relative)
    combo(ZH, ZH, 0, arow, brow, koff, acc);
    combo(ZH, ZH, 1, arow, brow, koff, acc);
    combo(ZH, ZL, 0, arow, brow, koff, acc);
    combo(ZH, ZL, 1, arow, brow, koff, acc);
    combo(ZL, ZH, 0, arow, brow, koff, acc);
    combo(ZL, ZH, 1, arow, brow, koff, acc);

    const float s = cs[0], c2 = cs[1];
    float sjv[4];
#pragma unroll
    for (int cg = 0; cg < 4; ++cg) sjv[cg] = s * sq[cbase + cg * 16 + l15];

    double dsum = 0.0;
#pragma unroll
    for (int rg = 0; rg < 4; ++rg) {
        // C/D map (m89): col = lane&15, row = (lane>>4)*4 + reg
        f32x4 si4 = *(const f32x4*)(sq + rbase + rg * 16 + lh * 4);
#pragma unroll
        for (int cg = 0; cg < 4; ++cg) {
            float ts = 0.f;
#pragma unroll
            for (int q = 0; q < 4; ++q) {
                float x = fmaf(c2, acc[rg][cg][q], fmaf(s, si4[q], sjv[cg]));
                x = fminf(x, 0.f);                     // clamp(L2,0) in exponent space
                float u  = fast_exp2(x);
                float u2 = u * u, u4 = u2 * u2;
                float su = fast_sqrt(u), qu = fast_sqrt(su);
                ts += ((u4 + u2) + (u + su)) + qu;
            }
            dsum += (double)ts;
        }
    }

#pragma unroll
    for (int off = 32; off; off >>= 1) dsum += __shfl_down(dsum, off);
    if (lane == 0) sred[wid] = dsum;
    __syncthreads();
    if (tid == 0) {
        double b = 0.0;
#pragma unroll
        for (int w = 0; w < 8; ++w) b += sred[w];
        const bool pos = (ib < 16) == (jb < 32);       // sign s_i*s_j, block-uniform
        atomicAdd(accS, pos ? b : -b);
    }
}

__global__ void k_fin(const double* __restrict__ accS, float* __restrict__ out)
{
    out[0] = (float)(accS[0] * (1.0 / ((double)NX * (double)NX)));
}

extern "C" void kernel_launch(void* const* d_in, const int* in_sizes, int n_in,
                              void* d_out, int out_size, void* d_ws, size_t ws_size,
                              hipStream_t stream)
{
    const float* X = (const float*)d_in[0];
    const float* Y = (const float*)d_in[1];

    char* ws = (char*)d_ws;
    double* sumsq  = (double*)(ws + 0);
    double* accS   = (double*)(ws + 8);
    float*  cs     = (float*)(ws + 16);
    float*  colsum = (float*)(ws + 64);                 // 64 f32
    float*  sq     = (float*)(ws + 512);                // 8192 f32
    ushort* ZH     = (ushort*)(ws + 65536);             // 1 MB
    ushort* ZL     = (ushort*)(ws + 65536 + 1048576);   // 1 MB

    hipMemsetAsync(d_ws, 0, 512, stream);               // accumulators + colsum
    k_sq   <<<512, 256, 0, stream>>>(X, Y, sq, sumsq);
    k_col  <<<32, 256, 0, stream>>>(X, Y, colsum);
    k_split<<<512, 256, 0, stream>>>(X, Y, ZH, ZL);
    k_bw   <<<1, 1, 0, stream>>>(sumsq, colsum, cs);
    k_main <<<dim3(32, 64), 512, 0, stream>>>(ZH, ZL, sq, cs, accS);
    k_fin  <<<1, 1, 0, stream>>>(accS, (float*)d_out);
}

// Round 7
// 121.447 us; speedup vs baseline: 3.8149x; 1.3516x over previous
//
#include <hip/hip_runtime.h>

// MMD loss. N=8192 rows (4096 X + 4096 Y), D=64, f32 in, f32 scalar out.
//   bandwidth: closed form  sum_ij L2 = 2N*sum(sq) - 2*||sum z||^2
//   main: dot via bf16 split (hh+hl+lh) MFMA 16x16x32; x4 = s4*L2 (s4=-log2e/(4bw))
//         K5 = v + v^2 + v^4 + v^8 + v^16,  v = 2^min(x4,0)
//   out = (sum_ij sign_i*sign_j*K5_ij) / 4096^2, finalized by last block.

#define NX 4096
#define NT 8192
#define DD 64

using f32x4 = __attribute__((ext_vector_type(4))) float;
using s8v   = __attribute__((ext_vector_type(8))) short;   // 8 bf16 = 4 VGPR

__device__ __forceinline__ float fast_exp2(float x) {
#if __has_builtin(__builtin_amdgcn_exp2f)
    return __builtin_amdgcn_exp2f(x);
#else
    return exp2f(x);
#endif
}
__device__ __forceinline__ ushort f2bf(float f) {          // RTNE f32 -> bf16 bits
    unsigned u = __float_as_uint(f);
    unsigned r = u + 0x7fffu + ((u >> 16) & 1u);
    return (ushort)(r >> 16);
}
__device__ __forceinline__ float bf2f(ushort h) {
    return __uint_as_float((unsigned)h << 16);
}

// ---- fused prep: sq[], sum(sq), colsum[64], bf16 hi/lo split ---------------
__global__ __launch_bounds__(512)
void k_prep(const float* __restrict__ X, const float* __restrict__ Y,
            ushort* __restrict__ ZH, ushort* __restrict__ ZL,
            float* __restrict__ sq, float* __restrict__ colsum,
            double* __restrict__ sumsq)
{
    __shared__ float colred[64];
    const int tid = threadIdx.x, bid = blockIdx.x;
    if (tid < 64) colred[tid] = 0.f;
    __syncthreads();

    const int sub = tid & 15;                 // float4 column group (invariant)
    float ca0 = 0.f, ca1 = 0.f, ca2 = 0.f, ca3 = 0.f;
    float ssq = 0.f;

#pragma unroll
    for (int k = 0; k < 8; ++k) {
        const int row = bid * 256 + k * 32 + (tid >> 4);
        const float4* zr = (const float4*)((row < NX) ? (X + (size_t)row * DD)
                                                      : (Y + (size_t)(row - NX) * DD));
        float4 v = zr[sub];

        ushort h0 = f2bf(v.x), h1 = f2bf(v.y), h2 = f2bf(v.z), h3 = f2bf(v.w);
        ushort l0 = f2bf(v.x - bf2f(h0)), l1 = f2bf(v.y - bf2f(h1));
        ushort l2 = f2bf(v.z - bf2f(h2)), l3 = f2bf(v.w - bf2f(h3));
        ((ushort4*)(ZH + (size_t)row * DD))[sub] = make_ushort4(h0, h1, h2, h3);
        ((ushort4*)(ZL + (size_t)row * DD))[sub] = make_ushort4(l0, l1, l2, l3);

        float d = fmaf(v.x, v.x, fmaf(v.y, v.y, fmaf(v.z, v.z, v.w * v.w)));
        ssq += d;
        float dr = d;
#pragma unroll
        for (int m = 1; m < 16; m <<= 1) dr += __shfl_xor(dr, m);
        if (sub == 0) sq[row] = dr;

        ca0 += v.x; ca1 += v.y; ca2 += v.z; ca3 += v.w;
    }

    // column sums: lanes sharing (lane&15) are {l, l+16, l+32, l+48}
    ca0 += __shfl_xor(ca0, 16); ca0 += __shfl_xor(ca0, 32);
    ca1 += __shfl_xor(ca1, 16); ca1 += __shfl_xor(ca1, 32);
    ca2 += __shfl_xor(ca2, 16); ca2 += __shfl_xor(ca2, 32);
    ca3 += __shfl_xor(ca3, 16); ca3 += __shfl_xor(ca3, 32);
    if ((tid & 63) < 16) {
        atomicAdd(&colred[sub * 4 + 0], ca0);
        atomicAdd(&colred[sub * 4 + 1], ca1);
        atomicAdd(&colred[sub * 4 + 2], ca2);
        atomicAdd(&colred[sub * 4 + 3], ca3);
    }

#pragma unroll
    for (int off = 32; off; off >>= 1) ssq += __shfl_down(ssq, off);
    if ((tid & 63) == 0) atomicAdd(sumsq, (double)ssq);

    __syncthreads();
    if (tid < 64) atomicAdd(&colsum[tid], colred[tid]);
}

// ---- main pairwise pass ----------------------------------------------------
// grid (32,16): block strip 256 i x 512 j, 8 iters of 64-wide j-tiles.
// 8 waves = 4(wr) x 2(wc); wave tile 64 i x 32 j per iter.
struct BFrag { s8v h[2][2]; s8v l[2][2]; };   // [cg][ks]

__global__ __launch_bounds__(512)
void k_main(const ushort* __restrict__ ZH, const ushort* __restrict__ ZL,
            const float* __restrict__ sq, const float* __restrict__ colsum,
            const double* __restrict__ sumsq,
            double* __restrict__ accS, unsigned* __restrict__ cnt,
            float* __restrict__ out)
{
    __shared__ double sred[8];
    const int tid = threadIdx.x, lane = tid & 63, wid = tid >> 6;
    const int wr = wid >> 1, wc = wid & 1;
    const int ib = blockIdx.x, jb = blockIdx.y;
    const int l15 = lane & 15, lh = lane >> 4;
    const int rbase = ib * 256 + wr * 64;

    // bandwidth constants (redundant per wave; colsum/sumsq are tiny + L2-hot)
    double cv = (double)colsum[lane]; cv *= cv;
#pragma unroll
    for (int m = 1; m < 64; m <<= 1) cv += __shfl_xor(cv, m);
    const double sl2 = 2.0 * (double)NT * sumsq[0] - 2.0 * cv;
    const double bwv = sl2 / ((double)NT * (double)NT - (double)NT);
    const float s4  = (float)(-0.36067376022224085 / bwv);   // -log2(e)/4 / bw
    const float c2q = -2.0f * s4;

    // A fragments + row-norm terms, cached for the whole strip
    s8v ah[4][2], al[4][2];
    f32x4 psi[4];
#pragma unroll
    for (int rg = 0; rg < 4; ++rg) {
#pragma unroll
        for (int ks = 0; ks < 2; ++ks) {
            size_t off = (size_t)(rbase + rg * 16 + l15) * DD + ks * 32 + lh * 8;
            ah[rg][ks] = *(const s8v*)(ZH + off);
            al[rg][ks] = *(const s8v*)(ZL + off);
        }
        f32x4 sv = *(const f32x4*)(sq + rbase + rg * 16 + lh * 4);
        psi[rg] = s4 * sv;
    }

    double dsum = 0.0;

    auto LOADB = [&](BFrag& b, int t) {
        const int cb = jb * 512 + t * 64 + wc * 32;
#pragma unroll
        for (int cg = 0; cg < 2; ++cg)
#pragma unroll
            for (int ks = 0; ks < 2; ++ks) {
                size_t off = (size_t)(cb + cg * 16 + l15) * DD + ks * 32 + lh * 8;
                b.h[cg][ks] = *(const s8v*)(ZH + off);
                b.l[cg][ks] = *(const s8v*)(ZL + off);
            }
    };

    auto STEP = [&](const BFrag& b, int t) {
        const int cb = jb * 512 + t * 64 + wc * 32;
        f32x4 acc[4][2];
#pragma unroll
        for (int rg = 0; rg < 4; ++rg)
#pragma unroll
            for (int cg = 0; cg < 2; ++cg)
                acc[rg][cg] = (f32x4){0.f, 0.f, 0.f, 0.f};
#pragma unroll
        for (int ks = 0; ks < 2; ++ks)
#pragma unroll
            for (int rg = 0; rg < 4; ++rg)
#pragma unroll
                for (int cg = 0; cg < 2; ++cg) {
                    acc[rg][cg] = __builtin_amdgcn_mfma_f32_16x16x32_bf16(ah[rg][ks], b.h[cg][ks], acc[rg][cg], 0, 0, 0);
                    acc[rg][cg] = __builtin_amdgcn_mfma_f32_16x16x32_bf16(ah[rg][ks], b.l[cg][ks], acc[rg][cg], 0, 0, 0);
                    acc[rg][cg] = __builtin_amdgcn_mfma_f32_16x16x32_bf16(al[rg][ks], b.h[cg][ks], acc[rg][cg], 0, 0, 0);
                }
        const float sj0 = s4 * sq[cb + l15];
        const float sj1 = s4 * sq[cb + 16 + l15];
        float bsum = 0.f;
#pragma unroll
        for (int rg = 0; rg < 4; ++rg)
#pragma unroll
            for (int cg = 0; cg < 2; ++cg) {
                const float sj = cg ? sj1 : sj0;
#pragma unroll
                for (int q = 0; q < 4; ++q) {
                    float x = fmaf(c2q, acc[rg][cg][q], psi[rg][q] + sj);
                    x = fminf(x, 0.f);                  // clamp(L2,0)
                    float v  = fast_exp2(x);            // u^(1/4)
                    float v2 = v * v, v4 = v2 * v2, v8 = v4 * v4, v16 = v8 * v8;
                    bsum += ((v16 + v8) + (v4 + v2)) + v;
                }
            }
        dsum += (double)bsum;
    };

    BFrag b0, b1;
    LOADB(b0, 0);
#pragma unroll
    for (int tp = 0; tp < 4; ++tp) {
        const int t0 = 2 * tp, t1 = t0 + 1;
        LOADB(b1, t1);
        STEP(b0, t0);
        if (t1 + 1 < 8) LOADB(b0, t1 + 1);
        STEP(b1, t1);
    }

#pragma unroll
    for (int off = 32; off; off >>= 1) dsum += __shfl_down(dsum, off);
    if (lane == 0) sred[wid] = dsum;
    __syncthreads();
    if (tid == 0) {
        double bsum = 0.0;
#pragma unroll
        for (int w = 0; w < 8; ++w) bsum += sred[w];
        const bool pos = (ib < 16) == (jb < 8);
        atomicAdd(accS, pos ? bsum : -bsum);
        __threadfence();
        unsigned old = atomicAdd(cnt, 1u);
        if (old == 32u * 16u - 1u) {                    // last block finalizes
            double S = atomicAdd(accS, 0.0);
            out[0] = (float)(S * (1.0 / ((double)NX * (double)NX)));
        }
    }
}

extern "C" void kernel_launch(void* const* d_in, const int* in_sizes, int n_in,
                              void* d_out, int out_size, void* d_ws, size_t ws_size,
                              hipStream_t stream)
{
    const float* X = (const float*)d_in[0];
    const float* Y = (const float*)d_in[1];

    char* ws = (char*)d_ws;
    double*   sumsq  = (double*)(ws + 0);
    double*   accS   = (double*)(ws + 8);
    unsigned* cnt    = (unsigned*)(ws + 16);
    float*    colsum = (float*)(ws + 64);               // 64 f32
    float*    sq     = (float*)(ws + 512);              // 8192 f32
    ushort*   ZH     = (ushort*)(ws + 65536);           // 1 MB
    ushort*   ZL     = (ushort*)(ws + 65536 + 1048576); // 1 MB

    hipMemsetAsync(d_ws, 0, 512, stream);
    k_prep<<<32, 512, 0, stream>>>(X, Y, ZH, ZL, sq, colsum, sumsq);
    k_main<<<dim3(32, 16), 512, 0, stream>>>(ZH, ZL, sq, colsum, sumsq,
                                             accS, cnt, (float*)d_out);
}